// Round 18
// baseline (185.942 us; speedup 1.0000x reference)
//
#include <hip/hip_runtime.h>
#include <hip/hip_bf16.h>
#include <stdint.h>

#define Q_NUM   2000000
#define T_NUM   200000
#define T_CURVE 20000
#define NF      8
#define NH      64
#define NOUT    3

// ws byte layout:
//   [0     .. 21503   ]  weight fragments (5120 dw) + epilogue table (256 dw)
//   [32768 .. +25.6MB ]  per-triangle records: 8 x float4   (validated r8)
#define WS_REC_OFF   32768
#define WS_NEED_REC  (WS_REC_OFF + (size_t)T_NUM * 128)

#define NWSF_W  5120
#define NWSF    5376

typedef float f32x16 __attribute__((ext_vector_type(16)));
typedef short s16x8  __attribute__((ext_vector_type(8)));

union FragU { int4 v; s16x8 s; unsigned u[4]; };

__device__ __forceinline__ unsigned short f2bf(float f) {
    __hip_bfloat16 h = __float2bfloat16(f);   // RNE
    unsigned short u; __builtin_memcpy(&u, &h, 2); return u;
}
__device__ __forceinline__ float bf2f(unsigned short u) {
    unsigned v = ((unsigned)u) << 16; float f; __builtin_memcpy(&f, &v, 4); return f;
}

// ================= setup kernel (validated r4/r5/r11) =================
__global__ void prep_w(const float* __restrict__ w1, const float* __restrict__ b1,
                       const float* __restrict__ w2, const float* __restrict__ b2,
                       const float* __restrict__ w3, unsigned* __restrict__ wsf) {
    const int l = threadIdx.x;  // 64 threads
    if (l >= 64) return;
    const int hb = l >> 5;
    for (int plane = 0; plane < 2; ++plane)
      for (int kb = 0; kb < 4; ++kb)
        for (int mb = 0; mb < 2; ++mb)
          for (int i = 0; i < 4; ++i) {
              const int j  = 32 * mb + (l & 31);
              const int k0 = 16 * kb + 8 * hb + 2 * i;
              const float v0 = w2[k0 * NH + j];
              const float v1 = w2[(k0 + 1) * NH + j];
              unsigned d;
              if (plane == 0) {
                  d = (unsigned)f2bf(v0) | ((unsigned)f2bf(v1) << 16);
              } else {
                  const float r0 = v0 - bf2f(f2bf(v0));
                  const float r1 = v1 - bf2f(f2bf(v1));
                  d = (unsigned)f2bf(r0) | ((unsigned)f2bf(r1) << 16);
              }
              wsf[(((plane * 4 + kb) * 2 + mb) * 64 + l) * 4 + i] = d;
          }
    for (int plane = 0; plane < 2; ++plane)
      for (int mb = 0; mb < 2; ++mb)
        for (int i = 0; i < 4; ++i) {
            const int j = 32 * mb + (l & 31);
            unsigned d = 0;
            if (hb == 0) {
                const int k0 = 2 * i;
                const float v0 = w1[k0 * NH + j];
                const float v1 = w1[(k0 + 1) * NH + j];
                if (plane == 0) {
                    d = (unsigned)f2bf(v0) | ((unsigned)f2bf(v1) << 16);
                } else {
                    const float r0 = v0 - bf2f(f2bf(v0));
                    const float r1 = v1 - bf2f(f2bf(v1));
                    d = (unsigned)f2bf(r0) | ((unsigned)f2bf(r1) << 16);
                }
            } else if (i == 0) {
                const float bv = b1[j];
                if (plane == 0) {
                    d = (unsigned)f2bf(bv);
                } else {
                    d = (unsigned)f2bf(bv - bf2f(f2bf(bv)));
                }
            }
            wsf[NWSF_W - 1024 + ((plane * 2 + mb) * 64 + l) * 4 + i] = d;
        }
    float4* ep = (float4*)&wsf[NWSF_W];
    ep[l] = make_float4(b2[l], w3[l * 3 + 0], w3[l * 3 + 1], w3[l * 3 + 2]);
}

// ================= per-triangle record builder (validated r8) =================
__global__ __launch_bounds__(256) void build_rec(
    const float* __restrict__ Vcont,
    const float* __restrict__ Vdisc,
    const float* __restrict__ Vcurv,
    const int*   __restrict__ T,
    const void*  __restrict__ VisCont,
    const int*   __restrict__ Tadj,
    const void*  __restrict__ Tsign,
    const int*   __restrict__ seco,
    float4* __restrict__ rec)
{
    const uint32_t* probe = (const uint32_t*)VisCont;
    uint32_t m = 0;
#pragma unroll
    for (int i = 0; i < 16; ++i) m |= probe[i];
    const bool bool_is_byte = (m > 1u);

    const int t = blockIdx.x * blockDim.x + threadIdx.x;
    if (t >= T_NUM) return;

    const int tv0 = T[t * 3 + 0];
    const int tv1 = T[t * 3 + 1];
    const int tv2 = T[t * 3 + 2];

    int d0 = Tadj[t * 6 + 0];
    int d1 = Tadj[t * 6 + 2];
    int d2 = Tadj[t * 6 + 4];

    const bool is_curved = (t < T_CURVE);
    if (is_curved) {
        const int s0 = seco[t * 2 + 0];
        const int s1 = seco[t * 2 + 1];
        if (s0 >= 0) d1 = s0;
        if (s1 >= 0) d2 = s1;
    }

    auto rdbool = [&](const void* p, int idx) -> bool {
        return bool_is_byte ? (((const uint8_t*)p)[idx] != 0)
                            : (((const int*)p)[idx] != 0);
    };

    const bool use0 = (!rdbool(VisCont, tv0)) && (d0 >= 0);
    const bool use1 = (!rdbool(VisCont, tv1)) && (d1 >= 0);
    const bool use2 = (!rdbool(VisCont, tv2)) && (d2 >= 0);

    const float4* c0p = (const float4*)(use0 ? &Vdisc[(size_t)d0 * NF] : &Vcont[(size_t)tv0 * NF]);
    const float4* c1p = (const float4*)(use1 ? &Vdisc[(size_t)d1 * NF] : &Vcont[(size_t)tv1 * NF]);
    const float4* c2p = (const float4*)(use2 ? &Vdisc[(size_t)d2 * NF] : &Vcont[(size_t)tv2 * NF]);

    float4* rp = &rec[(size_t)t * 8];
    rp[0] = c0p[0]; rp[1] = c0p[1];
    rp[2] = c1p[0]; rp[3] = c1p[1];
    rp[4] = c2p[0]; rp[5] = c2p[1];

    float4 cv0 = make_float4(0.f, 0.f, 0.f, 0.f);
    float4 cv1 = cv0;
    if (is_curved) {
        const float s = rdbool(Tsign, t) ? 1.0f : -1.0f;
        const float4* cvp = (const float4*)&Vcurv[(size_t)t * NF];
        float4 a = cvp[0], b = cvp[1];
        cv0 = make_float4(s * a.x, s * a.y, s * a.z, s * a.w);
        cv1 = make_float4(s * b.x, s * b.y, s * b.z, s * b.w);
    }
    rp[6] = cv0; rp[7] = cv1;
}

// ================= main fused kernel (r16 body) + 5-wave/EU register cap =================
__global__ __launch_bounds__(256, 5) void dann_main(
    const float* __restrict__ QT_uv,
    const int*   __restrict__ QT_idx,
    const float4* __restrict__ rec,
    const float* __restrict__ b3,
    const unsigned* __restrict__ wsf,
    float* __restrict__ out)
{
    __shared__ float4 eplds[64];
    if (threadIdx.x < 64)
        eplds[threadIdx.x] = ((const float4*)&wsf[NWSF_W])[threadIdx.x];

    const int q  = blockIdx.x * blockDim.x + threadIdx.x;
    const int qc = (q < Q_NUM) ? q : (Q_NUM - 1);   // clamp loads; store guarded
    const int  lane    = threadIdx.x & 63;
    const bool hb      = (lane >= 32);
    const bool lo_half = !hb;

    // ---- gather: issue rec load first; a1/interp schedule under its latency ----
    const float2 uv = ((const float2*)QT_uv)[qc];
    const int    t  = QT_idx[qc];
    const float4* rp = &rec[(size_t)t * 8];
    float4 r0 = rp[0], r1 = rp[1], r2 = rp[2], r3 = rp[3];
    float4 r4 = rp[4], r5 = rp[5], r6 = rp[6], r7 = rp[7];

    // layer-1 A-fragments: coalesced global loads (L2-hot 21KB)
    FragU a1[4];   // [plane*2+mb]
#pragma unroll
    for (int pm = 0; pm < 4; ++pm)
        a1[pm].v = *(const int4*)&wsf[NWSF_W - 1024 + (pm * 64 + lane) * 4];

    // ---- interp + pack (validated r8/r13 math) ----
    const float u  = uv.x;
    const float v  = uv.y;
    const float w0 = 1.0f - u - v;
    const float cf = 27.0f * w0 * u * v;   // sign folded into rec

    float feat[NF];
    {
        const float* a0 = (const float*)&r0;  const float* bb0 = (const float*)&r1;
        const float* c1 = (const float*)&r2;  const float* bb1 = (const float*)&r3;
        const float* c2 = (const float*)&r4;  const float* bb2 = (const float*)&r5;
        const float* av = (const float*)&r6;  const float* bv  = (const float*)&r7;
#pragma unroll
        for (int f = 0; f < 4; ++f) {
            feat[f]     = w0 * a0[f]  + u * c1[f]  + v * c2[f]  + cf * av[f];
            feat[f + 4] = w0 * bb0[f] + u * bb1[f] + v * bb2[f] + cf * bv[f];
        }
    }

    unsigned pfA[4];
#pragma unroll
    for (int i = 0; i < 4; ++i)
        pfA[i] = (unsigned)f2bf(feat[2 * i]) | ((unsigned)f2bf(feat[2 * i + 1]) << 16);
    unsigned pfB[4];
#pragma unroll
    for (int i = 0; i < 4; ++i) pfB[i] = (unsigned)__shfl_xor((int)pfA[i], 32);

    __syncthreads();   // eplds ready
    const float4* epb = eplds + (hb ? 4 : 0);

    // ---- B1 fragments for both query blocks ----
    FragU fbA, fbB;
    fbA.u[0] = hb ? 0x00003F80u : pfA[0];
    fbA.u[1] = hb ? 0u : pfA[1];
    fbA.u[2] = hb ? 0u : pfA[2];
    fbA.u[3] = hb ? 0u : pfA[3];
    fbB.u[0] = hb ? 0x00003F80u : pfB[0];
    fbB.u[1] = hb ? 0u : pfB[1];
    fbB.u[2] = hb ? 0u : pfB[2];
    fbB.u[3] = hb ? 0u : pfB[3];

    // ---- layer 1 both blocks, mb-sequential (validated r14) ----
    unsigned pkA[8][2], pkB[8][2];
#pragma unroll
    for (int mb = 0; mb < 2; ++mb) {
        f32x16 accA;
#pragma unroll
        for (int z = 0; z < 16; ++z) accA[z] = 0.f;
        accA = __builtin_amdgcn_mfma_f32_32x32x16_bf16(a1[0 * 2 + mb].s, fbA.s, accA, 0, 0, 0);
        accA = __builtin_amdgcn_mfma_f32_32x32x16_bf16(a1[1 * 2 + mb].s, fbA.s, accA, 0, 0, 0);
#pragma unroll
        for (int hh = 0; hh < 4; ++hh) {
            const int rb = 4 * hh;
            const float v0 = fmaxf(accA[rb + 0], 0.f);
            const float v1 = fmaxf(accA[rb + 1], 0.f);
            const float v2 = fmaxf(accA[rb + 2], 0.f);
            const float v3 = fmaxf(accA[rb + 3], 0.f);
            pkA[4 * mb + hh][0] = (unsigned)f2bf(v0) | ((unsigned)f2bf(v1) << 16);
            pkA[4 * mb + hh][1] = (unsigned)f2bf(v2) | ((unsigned)f2bf(v3) << 16);
        }
        f32x16 accB;
#pragma unroll
        for (int z = 0; z < 16; ++z) accB[z] = 0.f;
        accB = __builtin_amdgcn_mfma_f32_32x32x16_bf16(a1[0 * 2 + mb].s, fbB.s, accB, 0, 0, 0);
        accB = __builtin_amdgcn_mfma_f32_32x32x16_bf16(a1[1 * 2 + mb].s, fbB.s, accB, 0, 0, 0);
#pragma unroll
        for (int hh = 0; hh < 4; ++hh) {
            const int rb = 4 * hh;
            const float v0 = fmaxf(accB[rb + 0], 0.f);
            const float v1 = fmaxf(accB[rb + 1], 0.f);
            const float v2 = fmaxf(accB[rb + 2], 0.f);
            const float v3 = fmaxf(accB[rb + 3], 0.f);
            pkB[4 * mb + hh][0] = (unsigned)f2bf(v0) | ((unsigned)f2bf(v1) << 16);
            pkB[4 * mb + hh][1] = (unsigned)f2bf(v2) | ((unsigned)f2bf(v3) << 16);
        }
    }

    // ---- B2 fragments for both blocks (validated r11 exchange) ----
    FragU frA[4], frB[4];
#pragma unroll
    for (int kb = 0; kb < 4; ++kb) {
        {
            const unsigned own0 = hb ? pkA[2 * kb + 1][0] : pkA[2 * kb][0];
            const unsigned own1 = hb ? pkA[2 * kb + 1][1] : pkA[2 * kb][1];
            const unsigned X0   = hb ? pkA[2 * kb][0] : pkA[2 * kb + 1][0];
            const unsigned X1   = hb ? pkA[2 * kb][1] : pkA[2 * kb + 1][1];
            const unsigned Y0   = (unsigned)__shfl_xor((int)X0, 32);
            const unsigned Y1   = (unsigned)__shfl_xor((int)X1, 32);
            frA[kb].u[0] = hb ? Y0 : own0;
            frA[kb].u[1] = hb ? Y1 : own1;
            frA[kb].u[2] = hb ? own0 : Y0;
            frA[kb].u[3] = hb ? own1 : Y1;
        }
        {
            const unsigned own0 = hb ? pkB[2 * kb + 1][0] : pkB[2 * kb][0];
            const unsigned own1 = hb ? pkB[2 * kb + 1][1] : pkB[2 * kb][1];
            const unsigned X0   = hb ? pkB[2 * kb][0] : pkB[2 * kb + 1][0];
            const unsigned X1   = hb ? pkB[2 * kb][1] : pkB[2 * kb + 1][1];
            const unsigned Y0   = (unsigned)__shfl_xor((int)X0, 32);
            const unsigned Y1   = (unsigned)__shfl_xor((int)X1, 32);
            frB[kb].u[0] = hb ? Y0 : own0;
            frB[kb].u[1] = hb ? Y1 : own1;
            frB[kb].u[2] = hb ? own0 : Y0;
            frB[kb].u[3] = hb ? own1 : Y1;
        }
    }

    // ---- layer 2 + fold, mb-sequential; w2 frags per-mb from global, shared A/B ----
    float pA0 = 0.f, pA1 = 0.f, pA2 = 0.f;
    float pB0 = 0.f, pB1 = 0.f, pB2 = 0.f;
#pragma unroll
    for (int mb = 0; mb < 2; ++mb) {
        FragU w2f[8];   // [kb*2 + plane]
#pragma unroll
        for (int kb = 0; kb < 4; ++kb) {
            w2f[kb * 2 + 0].v = *(const int4*)&wsf[(((0 * 4 + kb) * 2 + mb) * 64 + lane) * 4];
            w2f[kb * 2 + 1].v = *(const int4*)&wsf[(((1 * 4 + kb) * 2 + mb) * 64 + lane) * 4];
        }
        f32x16 accA, accB;
#pragma unroll
        for (int z = 0; z < 16; ++z) { accA[z] = 0.f; accB[z] = 0.f; }
#pragma unroll
        for (int kb = 0; kb < 4; ++kb) {
            accA = __builtin_amdgcn_mfma_f32_32x32x16_bf16(w2f[kb * 2 + 0].s, frA[kb].s, accA, 0, 0, 0);
            accA = __builtin_amdgcn_mfma_f32_32x32x16_bf16(w2f[kb * 2 + 1].s, frA[kb].s, accA, 0, 0, 0);
            accB = __builtin_amdgcn_mfma_f32_32x32x16_bf16(w2f[kb * 2 + 0].s, frB[kb].s, accB, 0, 0, 0);
            accB = __builtin_amdgcn_mfma_f32_32x32x16_bf16(w2f[kb * 2 + 1].s, frB[kb].s, accB, 0, 0, 0);
        }
        // fold: one broadcast ep read serves both blocks (per-acc order unchanged)
#pragma unroll
        for (int r = 0; r < 16; ++r) {
            const int jr = (r & 3) + 8 * (r >> 2) + 32 * mb;   // compile-time
            const float4 e = epb[jr];                          // {b2, w3[0..2]}
            const float tA = fmaxf(accA[r] + e.x, 0.f);
            pA0 = fmaf(tA, e.y, pA0);
            pA1 = fmaf(tA, e.z, pA1);
            pA2 = fmaf(tA, e.w, pA2);
            const float tB = fmaxf(accB[r] + e.x, 0.f);
            pB0 = fmaf(tB, e.y, pB0);
            pB1 = fmaf(tB, e.z, pB1);
            pB2 = fmaf(tB, e.w, pB2);
        }
    }

    // ---- combine + store (validated r4/r11 epilogue) ----
    const float sA0 = pA0 + __shfl_xor(pA0, 32);
    const float sA1 = pA1 + __shfl_xor(pA1, 32);
    const float sA2 = pA2 + __shfl_xor(pA2, 32);
    const float sB0 = pB0 + __shfl_xor(pB0, 32);
    const float sB1 = pB1 + __shfl_xor(pB1, 32);
    const float sB2 = pB2 + __shfl_xor(pB2, 32);

    const float o0 = (lo_half ? sA0 : sB0) + b3[0];
    const float o1 = (lo_half ? sA1 : sB1) + b3[1];
    const float o2 = (lo_half ? sA2 : sB2) + b3[2];

    if (q < Q_NUM) {
        const size_t off = (size_t)q * NOUT;
        out[off + 0] = o0;
        out[off + 1] = o1;
        out[off + 2] = o2;
    }
}

// ================= fallback: r11-style fused table walk (small ws) =================
__device__ __forceinline__ void mlp_block(const unsigned src[4], bool hb, int lane,
                                          const unsigned* slds, const float4* epb,
                                          float& p0, float& p1, float& p2)
{
    FragU fb;
    fb.u[0] = hb ? 0x00003F80u : src[0];
    fb.u[1] = hb ? 0u : src[1];
    fb.u[2] = hb ? 0u : src[2];
    fb.u[3] = hb ? 0u : src[3];

    unsigned pk[8][2];
#pragma unroll
    for (int mb = 0; mb < 2; ++mb) {
        FragU a1hi, a1lo;
        a1hi.v = *(const int4*)&slds[NWSF_W - 1024 + ((0 * 2 + mb) * 64 + lane) * 4];
        a1lo.v = *(const int4*)&slds[NWSF_W - 1024 + ((1 * 2 + mb) * 64 + lane) * 4];
        f32x16 accA;
#pragma unroll
        for (int z = 0; z < 16; ++z) accA[z] = 0.f;
        accA = __builtin_amdgcn_mfma_f32_32x32x16_bf16(a1hi.s, fb.s, accA, 0, 0, 0);
        accA = __builtin_amdgcn_mfma_f32_32x32x16_bf16(a1lo.s, fb.s, accA, 0, 0, 0);
#pragma unroll
        for (int hh = 0; hh < 4; ++hh) {
            const int rb = 4 * hh;
            const float v0 = fmaxf(accA[rb + 0], 0.f);
            const float v1 = fmaxf(accA[rb + 1], 0.f);
            const float v2 = fmaxf(accA[rb + 2], 0.f);
            const float v3 = fmaxf(accA[rb + 3], 0.f);
            pk[4 * mb + hh][0] = (unsigned)f2bf(v0) | ((unsigned)f2bf(v1) << 16);
            pk[4 * mb + hh][1] = (unsigned)f2bf(v2) | ((unsigned)f2bf(v3) << 16);
        }
    }

    FragU fr[4];
#pragma unroll
    for (int kb = 0; kb < 4; ++kb) {
        const unsigned own0 = hb ? pk[2 * kb + 1][0] : pk[2 * kb][0];
        const unsigned own1 = hb ? pk[2 * kb + 1][1] : pk[2 * kb][1];
        const unsigned X0   = hb ? pk[2 * kb][0] : pk[2 * kb + 1][0];
        const unsigned X1   = hb ? pk[2 * kb][1] : pk[2 * kb + 1][1];
        const unsigned Y0   = (unsigned)__shfl_xor((int)X0, 32);
        const unsigned Y1   = (unsigned)__shfl_xor((int)X1, 32);
        fr[kb].u[0] = hb ? Y0 : own0;
        fr[kb].u[1] = hb ? Y1 : own1;
        fr[kb].u[2] = hb ? own0 : Y0;
        fr[kb].u[3] = hb ? own1 : Y1;
    }

#pragma unroll
    for (int mb = 0; mb < 2; ++mb) {
        f32x16 acc;
#pragma unroll
        for (int z = 0; z < 16; ++z) acc[z] = 0.f;
#pragma unroll
        for (int kb = 0; kb < 4; ++kb) {
            FragU ahi, alo;
            ahi.v = *(const int4*)&slds[(((0 * 4 + kb) * 2 + mb) * 64 + lane) * 4];
            alo.v = *(const int4*)&slds[(((1 * 4 + kb) * 2 + mb) * 64 + lane) * 4];
            acc = __builtin_amdgcn_mfma_f32_32x32x16_bf16(ahi.s, fr[kb].s, acc, 0, 0, 0);
            acc = __builtin_amdgcn_mfma_f32_32x32x16_bf16(alo.s, fr[kb].s, acc, 0, 0, 0);
        }
#pragma unroll
        for (int r = 0; r < 16; ++r) {
            const int jr = (r & 3) + 8 * (r >> 2) + 32 * mb;
            const float4 e = epb[jr];
            const float tv = fmaxf(acc[r] + e.x, 0.f);
            p0 = fmaf(tv, e.y, p0);
            p1 = fmaf(tv, e.z, p1);
            p2 = fmaf(tv, e.w, p2);
        }
    }
}

__global__ __launch_bounds__(256) void dann_fused_walk(
    const float* __restrict__ QT_uv,
    const float* __restrict__ Vcont,
    const float* __restrict__ Vdisc,
    const float* __restrict__ Vcurv,
    const float* __restrict__ b3,
    const int*   __restrict__ T,
    const int*   __restrict__ QT_idx,
    const void*  __restrict__ VisCont,
    const int*   __restrict__ Tadj,
    const void*  __restrict__ Tsign,
    const int*   __restrict__ seco,
    const unsigned* __restrict__ wsf,
    float* __restrict__ out)
{
    __shared__ unsigned slds[NWSF];
    for (int i = threadIdx.x; i < NWSF; i += 256) slds[i] = wsf[i];

    const int q  = blockIdx.x * blockDim.x + threadIdx.x;
    const int qc = (q < Q_NUM) ? q : (Q_NUM - 1);
    const int  lane    = threadIdx.x & 63;
    const bool hb      = (lane >= 32);
    const bool lo_half = !hb;

    const float2 uv = ((const float2*)QT_uv)[qc];
    const float u  = uv.x;
    const float v  = uv.y;
    const float w0 = 1.0f - u - v;
    const int   t  = QT_idx[qc];
    const float bub = 27.0f * w0 * u * v;

    const uint32_t* probe = (const uint32_t*)VisCont;
    uint32_t m = 0;
#pragma unroll
    for (int i = 0; i < 16; ++i) m |= probe[i];
    const bool bool_is_byte = (m > 1u);

    const int tv0 = T[t * 3 + 0];
    const int tv1 = T[t * 3 + 1];
    const int tv2 = T[t * 3 + 2];
    int d0 = Tadj[t * 6 + 0];
    int d1 = Tadj[t * 6 + 2];
    int d2 = Tadj[t * 6 + 4];
    const bool is_curved = (t < T_CURVE);
    const int  cid = is_curved ? t : (T_CURVE - 1);
    const int  s0 = seco[cid * 2 + 0];
    const int  s1 = seco[cid * 2 + 1];
    if (is_curved && s0 >= 0) d1 = s0;
    if (is_curved && s1 >= 0) d2 = s1;
    auto rdbool = [&](const void* p, int i) -> bool {
        return bool_is_byte ? (((const uint8_t*)p)[i] != 0)
                            : (((const int*)p)[i] != 0);
    };
    const bool use0 = (!rdbool(VisCont, tv0)) && (d0 >= 0);
    const bool use1 = (!rdbool(VisCont, tv1)) && (d1 >= 0);
    const bool use2 = (!rdbool(VisCont, tv2)) && (d2 >= 0);
    const float4* c0p = (const float4*)(use0 ? &Vdisc[(size_t)d0 * NF] : &Vcont[(size_t)tv0 * NF]);
    const float4* c1p = (const float4*)(use1 ? &Vdisc[(size_t)d1 * NF] : &Vcont[(size_t)tv1 * NF]);
    const float4* c2p = (const float4*)(use2 ? &Vdisc[(size_t)d2 * NF] : &Vcont[(size_t)tv2 * NF]);
    const float4 c0a = c0p[0], c0b = c0p[1];
    const float4 c1a = c1p[0], c1b = c1p[1];
    const float4 c2a = c2p[0], c2b = c2p[1];
    float cf = 0.0f;
    if (is_curved) cf = rdbool(Tsign, cid) ? bub : -bub;
    const float4* cvp = (const float4*)&Vcurv[(size_t)cid * NF];
    const float4 cva = cvp[0], cvb = cvp[1];

    float feat[NF];
    {
        const float* a0 = (const float*)&c0a;  const float* bb0 = (const float*)&c0b;
        const float* a1 = (const float*)&c1a;  const float* bb1 = (const float*)&c1b;
        const float* a2 = (const float*)&c2a;  const float* bb2 = (const float*)&c2b;
        const float* av = (const float*)&cva;  const float* bv  = (const float*)&cvb;
#pragma unroll
        for (int f = 0; f < 4; ++f) {
            feat[f]     = w0 * a0[f]  + u * a1[f]  + v * a2[f]  + cf * av[f];
            feat[f + 4] = w0 * bb0[f] + u * bb1[f] + v * bb2[f] + cf * bv[f];
        }
    }

    unsigned pf[4];
#pragma unroll
    for (int i = 0; i < 4; ++i)
        pf[i] = (unsigned)f2bf(feat[2 * i]) | ((unsigned)f2bf(feat[2 * i + 1]) << 16);

    __syncthreads();

    const float4* epb = (const float4*)&slds[NWSF_W] + (hb ? 4 : 0);

    float pA0 = 0.f, pA1 = 0.f, pA2 = 0.f;
    mlp_block(pf, hb, lane, slds, epb, pA0, pA1, pA2);

    unsigned pfx[4];
#pragma unroll
    for (int i = 0; i < 4; ++i) pfx[i] = (unsigned)__shfl_xor((int)pf[i], 32);
    float pB0 = 0.f, pB1 = 0.f, pB2 = 0.f;
    mlp_block(pfx, hb, lane, slds, epb, pB0, pB1, pB2);

    const float sA0 = pA0 + __shfl_xor(pA0, 32);
    const float sA1 = pA1 + __shfl_xor(pA1, 32);
    const float sA2 = pA2 + __shfl_xor(pA2, 32);
    const float sB0 = pB0 + __shfl_xor(pB0, 32);
    const float sB1 = pB1 + __shfl_xor(pB1, 32);
    const float sB2 = pB2 + __shfl_xor(pB2, 32);

    const float o0 = (lo_half ? sA0 : sB0) + b3[0];
    const float o1 = (lo_half ? sA1 : sB1) + b3[1];
    const float o2 = (lo_half ? sA2 : sB2) + b3[2];

    if (q < Q_NUM) {
        const size_t off = (size_t)q * NOUT;
        out[off + 0] = o0;
        out[off + 1] = o1;
        out[off + 2] = o2;
    }
}

extern "C" void kernel_launch(void* const* d_in, const int* in_sizes, int n_in,
                              void* d_out, int out_size, void* d_ws, size_t ws_size,
                              hipStream_t stream) {
    const float* QT_uv  = (const float*)d_in[2];
    const float* Vcont  = (const float*)d_in[3];
    const float* Vdisc  = (const float*)d_in[4];
    const float* Vcurv  = (const float*)d_in[5];
    const float* w1     = (const float*)d_in[6];
    const float* b1     = (const float*)d_in[7];
    const float* w2     = (const float*)d_in[8];
    const float* b2     = (const float*)d_in[9];
    const float* w3     = (const float*)d_in[10];
    const float* b3     = (const float*)d_in[11];
    const int*   T      = (const int*)d_in[12];
    const int*   QT_idx = (const int*)d_in[13];
    const void*  VisC   = d_in[14];
    const int*   Tadj   = (const int*)d_in[15];
    const void*  Tsign  = d_in[16];
    const int*   seco   = (const int*)d_in[17];
    float* out = (float*)d_out;

    unsigned* wsf = (unsigned*)d_ws;
    prep_w<<<1, 64, 0, stream>>>(w1, b1, w2, b2, w3, wsf);

    const int block = 256;
    const int grid  = (Q_NUM + block - 1) / block;

    if (ws_size >= WS_NEED_REC) {
        float4* rec = (float4*)((char*)d_ws + WS_REC_OFF);
        build_rec<<<(T_NUM + 255) / 256, 256, 0, stream>>>(Vcont, Vdisc, Vcurv,
                                                           T, VisC, Tadj, Tsign, seco, rec);
        dann_main<<<grid, block, 0, stream>>>(QT_uv, QT_idx, rec, b3, wsf, out);
    } else {
        dann_fused_walk<<<grid, block, 0, stream>>>(QT_uv, Vcont, Vdisc, Vcurv,
                                                    b3, T, QT_idx, VisC, Tadj, Tsign, seco,
                                                    wsf, out);
    }
}

// Round 19
// 102.967 us; speedup vs baseline: 1.8058x; 1.8058x over previous
//
#include <hip/hip_runtime.h>
#include <hip/hip_bf16.h>
#include <stdint.h>

#define Q_NUM   2000000
#define T_NUM   200000
#define T_CURVE 20000
#define NF      8
#define NH      64
#define NOUT    3

// ws byte layout:
//   [0     .. 21503   ]  weight fragments (5120 dw) + epilogue table (256 dw)
//   [32768 .. +25.6MB ]  per-triangle records: 8 x float4   (validated r8)
#define WS_REC_OFF   32768
#define WS_NEED_REC  (WS_REC_OFF + (size_t)T_NUM * 128)

#define NWSF_W  5120
#define NWSF    5376

typedef float f32x16 __attribute__((ext_vector_type(16)));
typedef short s16x8  __attribute__((ext_vector_type(8)));

union FragU { int4 v; s16x8 s; unsigned u[4]; };

__device__ __forceinline__ unsigned short f2bf(float f) {
    __hip_bfloat16 h = __float2bfloat16(f);   // RNE
    unsigned short u; __builtin_memcpy(&u, &h, 2); return u;
}
__device__ __forceinline__ float bf2f(unsigned short u) {
    unsigned v = ((unsigned)u) << 16; float f; __builtin_memcpy(&f, &v, 4); return f;
}

// ================= setup kernel (validated r4/r5/r11) =================
__global__ void prep_w(const float* __restrict__ w1, const float* __restrict__ b1,
                       const float* __restrict__ w2, const float* __restrict__ b2,
                       const float* __restrict__ w3, unsigned* __restrict__ wsf) {
    const int l = threadIdx.x;  // 64 threads
    if (l >= 64) return;
    const int hb = l >> 5;
    for (int plane = 0; plane < 2; ++plane)
      for (int kb = 0; kb < 4; ++kb)
        for (int mb = 0; mb < 2; ++mb)
          for (int i = 0; i < 4; ++i) {
              const int j  = 32 * mb + (l & 31);
              const int k0 = 16 * kb + 8 * hb + 2 * i;
              const float v0 = w2[k0 * NH + j];
              const float v1 = w2[(k0 + 1) * NH + j];
              unsigned d;
              if (plane == 0) {
                  d = (unsigned)f2bf(v0) | ((unsigned)f2bf(v1) << 16);
              } else {
                  const float r0 = v0 - bf2f(f2bf(v0));
                  const float r1 = v1 - bf2f(f2bf(v1));
                  d = (unsigned)f2bf(r0) | ((unsigned)f2bf(r1) << 16);
              }
              wsf[(((plane * 4 + kb) * 2 + mb) * 64 + l) * 4 + i] = d;
          }
    for (int plane = 0; plane < 2; ++plane)
      for (int mb = 0; mb < 2; ++mb)
        for (int i = 0; i < 4; ++i) {
            const int j = 32 * mb + (l & 31);
            unsigned d = 0;
            if (hb == 0) {
                const int k0 = 2 * i;
                const float v0 = w1[k0 * NH + j];
                const float v1 = w1[(k0 + 1) * NH + j];
                if (plane == 0) {
                    d = (unsigned)f2bf(v0) | ((unsigned)f2bf(v1) << 16);
                } else {
                    const float r0 = v0 - bf2f(f2bf(v0));
                    const float r1 = v1 - bf2f(f2bf(v1));
                    d = (unsigned)f2bf(r0) | ((unsigned)f2bf(r1) << 16);
                }
            } else if (i == 0) {
                const float bv = b1[j];
                if (plane == 0) {
                    d = (unsigned)f2bf(bv);
                } else {
                    d = (unsigned)f2bf(bv - bf2f(f2bf(bv)));
                }
            }
            wsf[NWSF_W - 1024 + ((plane * 2 + mb) * 64 + l) * 4 + i] = d;
        }
    float4* ep = (float4*)&wsf[NWSF_W];
    ep[l] = make_float4(b2[l], w3[l * 3 + 0], w3[l * 3 + 1], w3[l * 3 + 2]);
}

// ================= per-triangle record builder (validated r8) =================
__global__ __launch_bounds__(256) void build_rec(
    const float* __restrict__ Vcont,
    const float* __restrict__ Vdisc,
    const float* __restrict__ Vcurv,
    const int*   __restrict__ T,
    const void*  __restrict__ VisCont,
    const int*   __restrict__ Tadj,
    const void*  __restrict__ Tsign,
    const int*   __restrict__ seco,
    float4* __restrict__ rec)
{
    const uint32_t* probe = (const uint32_t*)VisCont;
    uint32_t m = 0;
#pragma unroll
    for (int i = 0; i < 16; ++i) m |= probe[i];
    const bool bool_is_byte = (m > 1u);

    const int t = blockIdx.x * blockDim.x + threadIdx.x;
    if (t >= T_NUM) return;

    const int tv0 = T[t * 3 + 0];
    const int tv1 = T[t * 3 + 1];
    const int tv2 = T[t * 3 + 2];

    int d0 = Tadj[t * 6 + 0];
    int d1 = Tadj[t * 6 + 2];
    int d2 = Tadj[t * 6 + 4];

    const bool is_curved = (t < T_CURVE);
    if (is_curved) {
        const int s0 = seco[t * 2 + 0];
        const int s1 = seco[t * 2 + 1];
        if (s0 >= 0) d1 = s0;
        if (s1 >= 0) d2 = s1;
    }

    auto rdbool = [&](const void* p, int idx) -> bool {
        return bool_is_byte ? (((const uint8_t*)p)[idx] != 0)
                            : (((const int*)p)[idx] != 0);
    };

    const bool use0 = (!rdbool(VisCont, tv0)) && (d0 >= 0);
    const bool use1 = (!rdbool(VisCont, tv1)) && (d1 >= 0);
    const bool use2 = (!rdbool(VisCont, tv2)) && (d2 >= 0);

    const float4* c0p = (const float4*)(use0 ? &Vdisc[(size_t)d0 * NF] : &Vcont[(size_t)tv0 * NF]);
    const float4* c1p = (const float4*)(use1 ? &Vdisc[(size_t)d1 * NF] : &Vcont[(size_t)tv1 * NF]);
    const float4* c2p = (const float4*)(use2 ? &Vdisc[(size_t)d2 * NF] : &Vcont[(size_t)tv2 * NF]);

    float4* rp = &rec[(size_t)t * 8];
    rp[0] = c0p[0]; rp[1] = c0p[1];
    rp[2] = c1p[0]; rp[3] = c1p[1];
    rp[4] = c2p[0]; rp[5] = c2p[1];

    float4 cv0 = make_float4(0.f, 0.f, 0.f, 0.f);
    float4 cv1 = cv0;
    if (is_curved) {
        const float s = rdbool(Tsign, t) ? 1.0f : -1.0f;
        const float4* cvp = (const float4*)&Vcurv[(size_t)t * NF];
        float4 a = cvp[0], b = cvp[1];
        cv0 = make_float4(s * a.x, s * a.y, s * a.z, s * a.w);
        cv1 = make_float4(s * b.x, s * b.y, s * b.z, s * b.w);
    }
    rp[6] = cv0; rp[7] = cv1;
}

// ================= main fused kernel (r16 body) + 4-wave/EU register cap (r17 optimum) =================
__global__ __launch_bounds__(256, 4) void dann_main(
    const float* __restrict__ QT_uv,
    const int*   __restrict__ QT_idx,
    const float4* __restrict__ rec,
    const float* __restrict__ b3,
    const unsigned* __restrict__ wsf,
    float* __restrict__ out)
{
    __shared__ float4 eplds[64];
    if (threadIdx.x < 64)
        eplds[threadIdx.x] = ((const float4*)&wsf[NWSF_W])[threadIdx.x];

    const int q  = blockIdx.x * blockDim.x + threadIdx.x;
    const int qc = (q < Q_NUM) ? q : (Q_NUM - 1);   // clamp loads; store guarded
    const int  lane    = threadIdx.x & 63;
    const bool hb      = (lane >= 32);
    const bool lo_half = !hb;

    // ---- gather: issue rec load first; a1/interp schedule under its latency ----
    const float2 uv = ((const float2*)QT_uv)[qc];
    const int    t  = QT_idx[qc];
    const float4* rp = &rec[(size_t)t * 8];
    float4 r0 = rp[0], r1 = rp[1], r2 = rp[2], r3 = rp[3];
    float4 r4 = rp[4], r5 = rp[5], r6 = rp[6], r7 = rp[7];

    // layer-1 A-fragments: coalesced global loads (L2-hot 21KB)
    FragU a1[4];   // [plane*2+mb]
#pragma unroll
    for (int pm = 0; pm < 4; ++pm)
        a1[pm].v = *(const int4*)&wsf[NWSF_W - 1024 + (pm * 64 + lane) * 4];

    // ---- interp + pack (validated r8/r13 math) ----
    const float u  = uv.x;
    const float v  = uv.y;
    const float w0 = 1.0f - u - v;
    const float cf = 27.0f * w0 * u * v;   // sign folded into rec

    float feat[NF];
    {
        const float* a0 = (const float*)&r0;  const float* bb0 = (const float*)&r1;
        const float* c1 = (const float*)&r2;  const float* bb1 = (const float*)&r3;
        const float* c2 = (const float*)&r4;  const float* bb2 = (const float*)&r5;
        const float* av = (const float*)&r6;  const float* bv  = (const float*)&r7;
#pragma unroll
        for (int f = 0; f < 4; ++f) {
            feat[f]     = w0 * a0[f]  + u * c1[f]  + v * c2[f]  + cf * av[f];
            feat[f + 4] = w0 * bb0[f] + u * bb1[f] + v * bb2[f] + cf * bv[f];
        }
    }

    unsigned pfA[4];
#pragma unroll
    for (int i = 0; i < 4; ++i)
        pfA[i] = (unsigned)f2bf(feat[2 * i]) | ((unsigned)f2bf(feat[2 * i + 1]) << 16);
    unsigned pfB[4];
#pragma unroll
    for (int i = 0; i < 4; ++i) pfB[i] = (unsigned)__shfl_xor((int)pfA[i], 32);

    __syncthreads();   // eplds ready
    const float4* epb = eplds + (hb ? 4 : 0);

    // ---- B1 fragments for both query blocks ----
    FragU fbA, fbB;
    fbA.u[0] = hb ? 0x00003F80u : pfA[0];
    fbA.u[1] = hb ? 0u : pfA[1];
    fbA.u[2] = hb ? 0u : pfA[2];
    fbA.u[3] = hb ? 0u : pfA[3];
    fbB.u[0] = hb ? 0x00003F80u : pfB[0];
    fbB.u[1] = hb ? 0u : pfB[1];
    fbB.u[2] = hb ? 0u : pfB[2];
    fbB.u[3] = hb ? 0u : pfB[3];

    // ---- layer 1 both blocks, mb-sequential (validated r14) ----
    unsigned pkA[8][2], pkB[8][2];
#pragma unroll
    for (int mb = 0; mb < 2; ++mb) {
        f32x16 accA;
#pragma unroll
        for (int z = 0; z < 16; ++z) accA[z] = 0.f;
        accA = __builtin_amdgcn_mfma_f32_32x32x16_bf16(a1[0 * 2 + mb].s, fbA.s, accA, 0, 0, 0);
        accA = __builtin_amdgcn_mfma_f32_32x32x16_bf16(a1[1 * 2 + mb].s, fbA.s, accA, 0, 0, 0);
#pragma unroll
        for (int hh = 0; hh < 4; ++hh) {
            const int rb = 4 * hh;
            const float v0 = fmaxf(accA[rb + 0], 0.f);
            const float v1 = fmaxf(accA[rb + 1], 0.f);
            const float v2 = fmaxf(accA[rb + 2], 0.f);
            const float v3 = fmaxf(accA[rb + 3], 0.f);
            pkA[4 * mb + hh][0] = (unsigned)f2bf(v0) | ((unsigned)f2bf(v1) << 16);
            pkA[4 * mb + hh][1] = (unsigned)f2bf(v2) | ((unsigned)f2bf(v3) << 16);
        }
        f32x16 accB;
#pragma unroll
        for (int z = 0; z < 16; ++z) accB[z] = 0.f;
        accB = __builtin_amdgcn_mfma_f32_32x32x16_bf16(a1[0 * 2 + mb].s, fbB.s, accB, 0, 0, 0);
        accB = __builtin_amdgcn_mfma_f32_32x32x16_bf16(a1[1 * 2 + mb].s, fbB.s, accB, 0, 0, 0);
#pragma unroll
        for (int hh = 0; hh < 4; ++hh) {
            const int rb = 4 * hh;
            const float v0 = fmaxf(accB[rb + 0], 0.f);
            const float v1 = fmaxf(accB[rb + 1], 0.f);
            const float v2 = fmaxf(accB[rb + 2], 0.f);
            const float v3 = fmaxf(accB[rb + 3], 0.f);
            pkB[4 * mb + hh][0] = (unsigned)f2bf(v0) | ((unsigned)f2bf(v1) << 16);
            pkB[4 * mb + hh][1] = (unsigned)f2bf(v2) | ((unsigned)f2bf(v3) << 16);
        }
    }

    // ---- B2 fragments for both blocks (validated r11 exchange) ----
    FragU frA[4], frB[4];
#pragma unroll
    for (int kb = 0; kb < 4; ++kb) {
        {
            const unsigned own0 = hb ? pkA[2 * kb + 1][0] : pkA[2 * kb][0];
            const unsigned own1 = hb ? pkA[2 * kb + 1][1] : pkA[2 * kb][1];
            const unsigned X0   = hb ? pkA[2 * kb][0] : pkA[2 * kb + 1][0];
            const unsigned X1   = hb ? pkA[2 * kb][1] : pkA[2 * kb + 1][1];
            const unsigned Y0   = (unsigned)__shfl_xor((int)X0, 32);
            const unsigned Y1   = (unsigned)__shfl_xor((int)X1, 32);
            frA[kb].u[0] = hb ? Y0 : own0;
            frA[kb].u[1] = hb ? Y1 : own1;
            frA[kb].u[2] = hb ? own0 : Y0;
            frA[kb].u[3] = hb ? own1 : Y1;
        }
        {
            const unsigned own0 = hb ? pkB[2 * kb + 1][0] : pkB[2 * kb][0];
            const unsigned own1 = hb ? pkB[2 * kb + 1][1] : pkB[2 * kb][1];
            const unsigned X0   = hb ? pkB[2 * kb][0] : pkB[2 * kb + 1][0];
            const unsigned X1   = hb ? pkB[2 * kb][1] : pkB[2 * kb + 1][1];
            const unsigned Y0   = (unsigned)__shfl_xor((int)X0, 32);
            const unsigned Y1   = (unsigned)__shfl_xor((int)X1, 32);
            frB[kb].u[0] = hb ? Y0 : own0;
            frB[kb].u[1] = hb ? Y1 : own1;
            frB[kb].u[2] = hb ? own0 : Y0;
            frB[kb].u[3] = hb ? own1 : Y1;
        }
    }

    // ---- layer 2 + fold, mb-sequential; w2 frags per-mb from global, shared A/B ----
    float pA0 = 0.f, pA1 = 0.f, pA2 = 0.f;
    float pB0 = 0.f, pB1 = 0.f, pB2 = 0.f;
#pragma unroll
    for (int mb = 0; mb < 2; ++mb) {
        FragU w2f[8];   // [kb*2 + plane]
#pragma unroll
        for (int kb = 0; kb < 4; ++kb) {
            w2f[kb * 2 + 0].v = *(const int4*)&wsf[(((0 * 4 + kb) * 2 + mb) * 64 + lane) * 4];
            w2f[kb * 2 + 1].v = *(const int4*)&wsf[(((1 * 4 + kb) * 2 + mb) * 64 + lane) * 4];
        }
        f32x16 accA, accB;
#pragma unroll
        for (int z = 0; z < 16; ++z) { accA[z] = 0.f; accB[z] = 0.f; }
#pragma unroll
        for (int kb = 0; kb < 4; ++kb) {
            accA = __builtin_amdgcn_mfma_f32_32x32x16_bf16(w2f[kb * 2 + 0].s, frA[kb].s, accA, 0, 0, 0);
            accA = __builtin_amdgcn_mfma_f32_32x32x16_bf16(w2f[kb * 2 + 1].s, frA[kb].s, accA, 0, 0, 0);
            accB = __builtin_amdgcn_mfma_f32_32x32x16_bf16(w2f[kb * 2 + 0].s, frB[kb].s, accB, 0, 0, 0);
            accB = __builtin_amdgcn_mfma_f32_32x32x16_bf16(w2f[kb * 2 + 1].s, frB[kb].s, accB, 0, 0, 0);
        }
        // fold: one broadcast ep read serves both blocks (per-acc order unchanged)
#pragma unroll
        for (int r = 0; r < 16; ++r) {
            const int jr = (r & 3) + 8 * (r >> 2) + 32 * mb;   // compile-time
            const float4 e = epb[jr];                          // {b2, w3[0..2]}
            const float tA = fmaxf(accA[r] + e.x, 0.f);
            pA0 = fmaf(tA, e.y, pA0);
            pA1 = fmaf(tA, e.z, pA1);
            pA2 = fmaf(tA, e.w, pA2);
            const float tB = fmaxf(accB[r] + e.x, 0.f);
            pB0 = fmaf(tB, e.y, pB0);
            pB1 = fmaf(tB, e.z, pB1);
            pB2 = fmaf(tB, e.w, pB2);
        }
    }

    // ---- combine + store (validated r4/r11 epilogue) ----
    const float sA0 = pA0 + __shfl_xor(pA0, 32);
    const float sA1 = pA1 + __shfl_xor(pA1, 32);
    const float sA2 = pA2 + __shfl_xor(pA2, 32);
    const float sB0 = pB0 + __shfl_xor(pB0, 32);
    const float sB1 = pB1 + __shfl_xor(pB1, 32);
    const float sB2 = pB2 + __shfl_xor(pB2, 32);

    const float o0 = (lo_half ? sA0 : sB0) + b3[0];
    const float o1 = (lo_half ? sA1 : sB1) + b3[1];
    const float o2 = (lo_half ? sA2 : sB2) + b3[2];

    if (q < Q_NUM) {
        const size_t off = (size_t)q * NOUT;
        out[off + 0] = o0;
        out[off + 1] = o1;
        out[off + 2] = o2;
    }
}

// ================= fallback: r11-style fused table walk (small ws) =================
__device__ __forceinline__ void mlp_block(const unsigned src[4], bool hb, int lane,
                                          const unsigned* slds, const float4* epb,
                                          float& p0, float& p1, float& p2)
{
    FragU fb;
    fb.u[0] = hb ? 0x00003F80u : src[0];
    fb.u[1] = hb ? 0u : src[1];
    fb.u[2] = hb ? 0u : src[2];
    fb.u[3] = hb ? 0u : src[3];

    unsigned pk[8][2];
#pragma unroll
    for (int mb = 0; mb < 2; ++mb) {
        FragU a1hi, a1lo;
        a1hi.v = *(const int4*)&slds[NWSF_W - 1024 + ((0 * 2 + mb) * 64 + lane) * 4];
        a1lo.v = *(const int4*)&slds[NWSF_W - 1024 + ((1 * 2 + mb) * 64 + lane) * 4];
        f32x16 accA;
#pragma unroll
        for (int z = 0; z < 16; ++z) accA[z] = 0.f;
        accA = __builtin_amdgcn_mfma_f32_32x32x16_bf16(a1hi.s, fb.s, accA, 0, 0, 0);
        accA = __builtin_amdgcn_mfma_f32_32x32x16_bf16(a1lo.s, fb.s, accA, 0, 0, 0);
#pragma unroll
        for (int hh = 0; hh < 4; ++hh) {
            const int rb = 4 * hh;
            const float v0 = fmaxf(accA[rb + 0], 0.f);
            const float v1 = fmaxf(accA[rb + 1], 0.f);
            const float v2 = fmaxf(accA[rb + 2], 0.f);
            const float v3 = fmaxf(accA[rb + 3], 0.f);
            pk[4 * mb + hh][0] = (unsigned)f2bf(v0) | ((unsigned)f2bf(v1) << 16);
            pk[4 * mb + hh][1] = (unsigned)f2bf(v2) | ((unsigned)f2bf(v3) << 16);
        }
    }

    FragU fr[4];
#pragma unroll
    for (int kb = 0; kb < 4; ++kb) {
        const unsigned own0 = hb ? pk[2 * kb + 1][0] : pk[2 * kb][0];
        const unsigned own1 = hb ? pk[2 * kb + 1][1] : pk[2 * kb][1];
        const unsigned X0   = hb ? pk[2 * kb][0] : pk[2 * kb + 1][0];
        const unsigned X1   = hb ? pk[2 * kb][1] : pk[2 * kb + 1][1];
        const unsigned Y0   = (unsigned)__shfl_xor((int)X0, 32);
        const unsigned Y1   = (unsigned)__shfl_xor((int)X1, 32);
        fr[kb].u[0] = hb ? Y0 : own0;
        fr[kb].u[1] = hb ? Y1 : own1;
        fr[kb].u[2] = hb ? own0 : Y0;
        fr[kb].u[3] = hb ? own1 : Y1;
    }

#pragma unroll
    for (int mb = 0; mb < 2; ++mb) {
        f32x16 acc;
#pragma unroll
        for (int z = 0; z < 16; ++z) acc[z] = 0.f;
#pragma unroll
        for (int kb = 0; kb < 4; ++kb) {
            FragU ahi, alo;
            ahi.v = *(const int4*)&slds[(((0 * 4 + kb) * 2 + mb) * 64 + lane) * 4];
            alo.v = *(const int4*)&slds[(((1 * 4 + kb) * 2 + mb) * 64 + lane) * 4];
            acc = __builtin_amdgcn_mfma_f32_32x32x16_bf16(ahi.s, fr[kb].s, acc, 0, 0, 0);
            acc = __builtin_amdgcn_mfma_f32_32x32x16_bf16(alo.s, fr[kb].s, acc, 0, 0, 0);
        }
#pragma unroll
        for (int r = 0; r < 16; ++r) {
            const int jr = (r & 3) + 8 * (r >> 2) + 32 * mb;
            const float4 e = epb[jr];
            const float tv = fmaxf(acc[r] + e.x, 0.f);
            p0 = fmaf(tv, e.y, p0);
            p1 = fmaf(tv, e.z, p1);
            p2 = fmaf(tv, e.w, p2);
        }
    }
}

__global__ __launch_bounds__(256) void dann_fused_walk(
    const float* __restrict__ QT_uv,
    const float* __restrict__ Vcont,
    const float* __restrict__ Vdisc,
    const float* __restrict__ Vcurv,
    const float* __restrict__ b3,
    const int*   __restrict__ T,
    const int*   __restrict__ QT_idx,
    const void*  __restrict__ VisCont,
    const int*   __restrict__ Tadj,
    const void*  __restrict__ Tsign,
    const int*   __restrict__ seco,
    const unsigned* __restrict__ wsf,
    float* __restrict__ out)
{
    __shared__ unsigned slds[NWSF];
    for (int i = threadIdx.x; i < NWSF; i += 256) slds[i] = wsf[i];

    const int q  = blockIdx.x * blockDim.x + threadIdx.x;
    const int qc = (q < Q_NUM) ? q : (Q_NUM - 1);
    const int  lane    = threadIdx.x & 63;
    const bool hb      = (lane >= 32);
    const bool lo_half = !hb;

    const float2 uv = ((const float2*)QT_uv)[qc];
    const float u  = uv.x;
    const float v  = uv.y;
    const float w0 = 1.0f - u - v;
    const int   t  = QT_idx[qc];
    const float bub = 27.0f * w0 * u * v;

    const uint32_t* probe = (const uint32_t*)VisCont;
    uint32_t m = 0;
#pragma unroll
    for (int i = 0; i < 16; ++i) m |= probe[i];
    const bool bool_is_byte = (m > 1u);

    const int tv0 = T[t * 3 + 0];
    const int tv1 = T[t * 3 + 1];
    const int tv2 = T[t * 3 + 2];
    int d0 = Tadj[t * 6 + 0];
    int d1 = Tadj[t * 6 + 2];
    int d2 = Tadj[t * 6 + 4];
    const bool is_curved = (t < T_CURVE);
    const int  cid = is_curved ? t : (T_CURVE - 1);
    const int  s0 = seco[cid * 2 + 0];
    const int  s1 = seco[cid * 2 + 1];
    if (is_curved && s0 >= 0) d1 = s0;
    if (is_curved && s1 >= 0) d2 = s1;
    auto rdbool = [&](const void* p, int i) -> bool {
        return bool_is_byte ? (((const uint8_t*)p)[i] != 0)
                            : (((const int*)p)[i] != 0);
    };
    const bool use0 = (!rdbool(VisCont, tv0)) && (d0 >= 0);
    const bool use1 = (!rdbool(VisCont, tv1)) && (d1 >= 0);
    const bool use2 = (!rdbool(VisCont, tv2)) && (d2 >= 0);
    const float4* c0p = (const float4*)(use0 ? &Vdisc[(size_t)d0 * NF] : &Vcont[(size_t)tv0 * NF]);
    const float4* c1p = (const float4*)(use1 ? &Vdisc[(size_t)d1 * NF] : &Vcont[(size_t)tv1 * NF]);
    const float4* c2p = (const float4*)(use2 ? &Vdisc[(size_t)d2 * NF] : &Vcont[(size_t)tv2 * NF]);
    const float4 c0a = c0p[0], c0b = c0p[1];
    const float4 c1a = c1p[0], c1b = c1p[1];
    const float4 c2a = c2p[0], c2b = c2p[1];
    float cf = 0.0f;
    if (is_curved) cf = rdbool(Tsign, cid) ? bub : -bub;
    const float4* cvp = (const float4*)&Vcurv[(size_t)cid * NF];
    const float4 cva = cvp[0], cvb = cvp[1];

    float feat[NF];
    {
        const float* a0 = (const float*)&c0a;  const float* bb0 = (const float*)&c0b;
        const float* a1 = (const float*)&c1a;  const float* bb1 = (const float*)&c1b;
        const float* a2 = (const float*)&c2a;  const float* bb2 = (const float*)&c2b;
        const float* av = (const float*)&cva;  const float* bv  = (const float*)&cvb;
#pragma unroll
        for (int f = 0; f < 4; ++f) {
            feat[f]     = w0 * a0[f]  + u * a1[f]  + v * a2[f]  + cf * av[f];
            feat[f + 4] = w0 * bb0[f] + u * bb1[f] + v * bb2[f] + cf * bv[f];
        }
    }

    unsigned pf[4];
#pragma unroll
    for (int i = 0; i < 4; ++i)
        pf[i] = (unsigned)f2bf(feat[2 * i]) | ((unsigned)f2bf(feat[2 * i + 1]) << 16);

    __syncthreads();

    const float4* epb = (const float4*)&slds[NWSF_W] + (hb ? 4 : 0);

    float pA0 = 0.f, pA1 = 0.f, pA2 = 0.f;
    mlp_block(pf, hb, lane, slds, epb, pA0, pA1, pA2);

    unsigned pfx[4];
#pragma unroll
    for (int i = 0; i < 4; ++i) pfx[i] = (unsigned)__shfl_xor((int)pf[i], 32);
    float pB0 = 0.f, pB1 = 0.f, pB2 = 0.f;
    mlp_block(pfx, hb, lane, slds, epb, pB0, pB1, pB2);

    const float sA0 = pA0 + __shfl_xor(pA0, 32);
    const float sA1 = pA1 + __shfl_xor(pA1, 32);
    const float sA2 = pA2 + __shfl_xor(pA2, 32);
    const float sB0 = pB0 + __shfl_xor(pB0, 32);
    const float sB1 = pB1 + __shfl_xor(pB1, 32);
    const float sB2 = pB2 + __shfl_xor(pB2, 32);

    const float o0 = (lo_half ? sA0 : sB0) + b3[0];
    const float o1 = (lo_half ? sA1 : sB1) + b3[1];
    const float o2 = (lo_half ? sA2 : sB2) + b3[2];

    if (q < Q_NUM) {
        const size_t off = (size_t)q * NOUT;
        out[off + 0] = o0;
        out[off + 1] = o1;
        out[off + 2] = o2;
    }
}

extern "C" void kernel_launch(void* const* d_in, const int* in_sizes, int n_in,
                              void* d_out, int out_size, void* d_ws, size_t ws_size,
                              hipStream_t stream) {
    const float* QT_uv  = (const float*)d_in[2];
    const float* Vcont  = (const float*)d_in[3];
    const float* Vdisc  = (const float*)d_in[4];
    const float* Vcurv  = (const float*)d_in[5];
    const float* w1     = (const float*)d_in[6];
    const float* b1     = (const float*)d_in[7];
    const float* w2     = (const float*)d_in[8];
    const float* b2     = (const float*)d_in[9];
    const float* w3     = (const float*)d_in[10];
    const float* b3     = (const float*)d_in[11];
    const int*   T      = (const int*)d_in[12];
    const int*   QT_idx = (const int*)d_in[13];
    const void*  VisC   = d_in[14];
    const int*   Tadj   = (const int*)d_in[15];
    const void*  Tsign  = d_in[16];
    const int*   seco   = (const int*)d_in[17];
    float* out = (float*)d_out;

    unsigned* wsf = (unsigned*)d_ws;
    prep_w<<<1, 64, 0, stream>>>(w1, b1, w2, b2, w3, wsf);

    const int block = 256;
    const int grid  = (Q_NUM + block - 1) / block;

    if (ws_size >= WS_NEED_REC) {
        float4* rec = (float4*)((char*)d_ws + WS_REC_OFF);
        build_rec<<<(T_NUM + 255) / 256, 256, 0, stream>>>(Vcont, Vdisc, Vcurv,
                                                           T, VisC, Tadj, Tsign, seco, rec);
        dann_main<<<grid, block, 0, stream>>>(QT_uv, QT_idx, rec, b3, wsf, out);
    } else {
        dann_fused_walk<<<grid, block, 0, stream>>>(QT_uv, Vcont, Vdisc, Vcurv,
                                                    b3, T, QT_idx, VisC, Tadj, Tsign, seco,
                                                    wsf, out);
    }
}